// Round 2
// baseline (262.003 us; speedup 1.0000x reference)
//
#include <hip/hip_runtime.h>

// WaveletParsingLayer: per-row stable stream compaction.
// x3[B,C,L] -> out[B,C,KEEP], dropping elements == FILLER (10.1f), order-preserving.
// x1, x2 are unused by the reference.

#define FILLER_VAL 10.1f
constexpr int L_LEN = 16384;
constexpr int KEEP_LEN = 12288;
constexpr int BLOCK = 256;           // 4 waves of 64
constexpr int CHUNK = BLOCK * 4;     // 1024 elements per iteration (float4/thread)

__global__ __launch_bounds__(BLOCK) void compact_rows_kernel(
    const float* __restrict__ x3, float* __restrict__ out)
{
    const int row = blockIdx.x;
    const float* __restrict__ in = x3 + (size_t)row * L_LEN;
    float* __restrict__ o = out + (size_t)row * KEEP_LEN;

    const int tid  = threadIdx.x;
    const int lane = tid & 63;
    const int wid  = tid >> 6;

    __shared__ int wave_tot[BLOCK / 64];

    const unsigned long long lt_mask = (1ULL << lane) - 1ULL;

    int base = 0;  // running count of survivors emitted so far (uniform across block)

    #pragma unroll 1
    for (int chunk = 0; chunk < L_LEN; chunk += CHUNK) {
        float4 v = *reinterpret_cast<const float4*>(in + chunk + tid * 4);

        const bool p0 = v.x != FILLER_VAL;
        const bool p1 = v.y != FILLER_VAL;
        const bool p2 = v.z != FILLER_VAL;
        const bool p3 = v.w != FILLER_VAL;

        // Per-element ballot across the 64-lane wave. Element order within the
        // chunk is (lane-major, then j): global idx = chunk + 4*tid + j, so the
        // prefix for (lane, j) = sum of counts of lanes < lane  +  own j' < j.
        const unsigned long long m0 = __ballot(p0);
        const unsigned long long m1 = __ballot(p1);
        const unsigned long long m2 = __ballot(p2);
        const unsigned long long m3 = __ballot(p3);

        const int before = __popcll(m0 & lt_mask) + __popcll(m1 & lt_mask)
                         + __popcll(m2 & lt_mask) + __popcll(m3 & lt_mask);
        const int wtot   = __popcll(m0) + __popcll(m1) + __popcll(m2) + __popcll(m3);

        if (lane == 0) wave_tot[wid] = wtot;
        __syncthreads();

        int wave_base = 0;
        #pragma unroll
        for (int w = 0; w < BLOCK / 64; ++w) {
            if (w < wid) wave_base += wave_tot[w];
        }
        int chunk_total = 0;
        #pragma unroll
        for (int w = 0; w < BLOCK / 64; ++w) chunk_total += wave_tot[w];

        int pos = base + wave_base + before;

        if (p0) { if (pos < KEEP_LEN) o[pos] = v.x; ++pos; }
        if (p1) { if (pos < KEEP_LEN) o[pos] = v.y; ++pos; }
        if (p2) { if (pos < KEEP_LEN) o[pos] = v.z; ++pos; }
        if (p3) { if (pos < KEEP_LEN) o[pos] = v.w; ++pos; }

        base += chunk_total;
        __syncthreads();  // protect wave_tot before next iteration overwrites it
    }
}

extern "C" void kernel_launch(void* const* d_in, const int* in_sizes, int n_in,
                              void* d_out, int out_size, void* d_ws, size_t ws_size,
                              hipStream_t stream)
{
    // in order: x1 [B,C,4096] f32 (unused), x2 [B,C,4096] f32 (unused),
    //           x3 [B,C,L] f32, keep_len (scalar int, value 12288)
    const float* x3 = (const float*)d_in[2];
    float* out = (float*)d_out;

    const int rows = in_sizes[2] / L_LEN;  // B*C = 2048

    compact_rows_kernel<<<rows, BLOCK, 0, stream>>>(x3, out);
}

// Round 3
// 258.959 us; speedup vs baseline: 1.0118x; 1.0118x over previous
//
#include <hip/hip_runtime.h>

// WaveletParsingLayer: per-row stable stream compaction.
// x3[B,C,L] -> out[B,C,KEEP], dropping elements == FILLER (10.1f), order-preserving.
// x1, x2 are unused by the reference.
//
// R3: whole row register-resident (16 float4/thread, all loads in flight at
// once), 2 barriers per block (two 8-chunk halves, double-buffered wave
// totals). R2 post-mortem showed the limiter was the 16x serialized
// load->ballot->barrier chain (~12K cyc/chunk), not bandwidth.

#define FILLER_VAL 10.1f
constexpr int L_LEN   = 16384;
constexpr int KEEP_LEN = 12288;
constexpr int BLOCK   = 256;          // 4 waves of 64
constexpr int NW      = BLOCK / 64;   // waves per block
constexpr int CHUNK   = BLOCK * 4;    // 1024 elements per chunk
constexpr int HC      = 8;            // chunks per half (8*1024 = half row)

__global__ __launch_bounds__(BLOCK) void compact_rows_kernel(
    const float* __restrict__ x3, float* __restrict__ out)
{
    const int row = blockIdx.x;
    const float* __restrict__ in = x3 + (size_t)row * L_LEN;
    float* __restrict__ o = out + (size_t)row * KEEP_LEN;

    const int tid  = threadIdx.x;
    const int lane = tid & 63;
    const int wid  = tid >> 6;
    const unsigned long long lt = (1ULL << lane) - 1ULL;

    __shared__ int wtot[2][HC][NW];   // [half][chunk][wave] survivor counts

    // ---- Issue ALL 16 loads up front (independent, 16 outstanding dwordx4).
    float4 va[HC], vb[HC];
    #pragma unroll
    for (int c = 0; c < HC; ++c)
        va[c] = *reinterpret_cast<const float4*>(in + c * CHUNK + tid * 4);
    #pragma unroll
    for (int c = 0; c < HC; ++c)
        vb[c] = *reinterpret_cast<const float4*>(in + (HC + c) * CHUNK + tid * 4);

    // ---- Half A: per-chunk ballots -> lane prefix + wave totals.
    // Element order within (chunk, wave): idx = chunk*1024 + wave*256 + lane*4 + j.
    // So "before me" = all 4 elems of earlier lanes (popcll of each mask & lt);
    // own j'<j is handled by pos++ at store time.
    int before_a[HC];
    #pragma unroll
    for (int c = 0; c < HC; ++c) {
        unsigned long long m0 = __ballot(va[c].x != FILLER_VAL);
        unsigned long long m1 = __ballot(va[c].y != FILLER_VAL);
        unsigned long long m2 = __ballot(va[c].z != FILLER_VAL);
        unsigned long long m3 = __ballot(va[c].w != FILLER_VAL);
        before_a[c] = __popcll(m0 & lt) + __popcll(m1 & lt)
                    + __popcll(m2 & lt) + __popcll(m3 & lt);
        if (lane == 0)
            wtot[0][c][wid] = __popcll(m0) + __popcll(m1)
                            + __popcll(m2) + __popcll(m3);
    }
    __syncthreads();   // barrier 1: wtot[0] visible

    // ---- Half A emit: walk chunk/wave totals (LDS broadcast reads),
    // accumulate running base, scatter survivors.
    int run = 0;
    #pragma unroll
    for (int c = 0; c < HC; ++c) {
        int wb = run;
        #pragma unroll
        for (int w = 0; w < NW; ++w) {
            int t = wtot[0][c][w];
            if (w < wid) wb += t;
            run += t;
        }
        int pos = wb + before_a[c];
        float4 v = va[c];
        if (v.x != FILLER_VAL) { if (pos < KEEP_LEN) o[pos] = v.x; ++pos; }
        if (v.y != FILLER_VAL) { if (pos < KEEP_LEN) o[pos] = v.y; ++pos; }
        if (v.z != FILLER_VAL) { if (pos < KEEP_LEN) o[pos] = v.z; ++pos; }
        if (v.w != FILLER_VAL) { if (pos < KEEP_LEN) o[pos] = v.w; ++pos; }
    }

    // ---- Half B counts (vb already in flight since the top).
    int before_b[HC];
    #pragma unroll
    for (int c = 0; c < HC; ++c) {
        unsigned long long m0 = __ballot(vb[c].x != FILLER_VAL);
        unsigned long long m1 = __ballot(vb[c].y != FILLER_VAL);
        unsigned long long m2 = __ballot(vb[c].z != FILLER_VAL);
        unsigned long long m3 = __ballot(vb[c].w != FILLER_VAL);
        before_b[c] = __popcll(m0 & lt) + __popcll(m1 & lt)
                    + __popcll(m2 & lt) + __popcll(m3 & lt);
        if (lane == 0)
            wtot[1][c][wid] = __popcll(m0) + __popcll(m1)
                            + __popcll(m2) + __popcll(m3);
    }
    __syncthreads();   // barrier 2: wtot[1] visible

    // ---- Half B emit. `run` already holds half A's total survivors.
    #pragma unroll
    for (int c = 0; c < HC; ++c) {
        int wb = run;
        #pragma unroll
        for (int w = 0; w < NW; ++w) {
            int t = wtot[1][c][w];
            if (w < wid) wb += t;
            run += t;
        }
        int pos = wb + before_b[c];
        float4 v = vb[c];
        if (v.x != FILLER_VAL) { if (pos < KEEP_LEN) o[pos] = v.x; ++pos; }
        if (v.y != FILLER_VAL) { if (pos < KEEP_LEN) o[pos] = v.y; ++pos; }
        if (v.z != FILLER_VAL) { if (pos < KEEP_LEN) o[pos] = v.z; ++pos; }
        if (v.w != FILLER_VAL) { if (pos < KEEP_LEN) o[pos] = v.w; ++pos; }
    }
}

extern "C" void kernel_launch(void* const* d_in, const int* in_sizes, int n_in,
                              void* d_out, int out_size, void* d_ws, size_t ws_size,
                              hipStream_t stream)
{
    // in order: x1 [B,C,4096] f32 (unused), x2 [B,C,4096] f32 (unused),
    //           x3 [B,C,L] f32, keep_len (scalar int, value 12288)
    const float* x3 = (const float*)d_in[2];
    float* out = (float*)d_out;

    const int rows = in_sizes[2] / L_LEN;  // B*C = 2048

    compact_rows_kernel<<<rows, BLOCK, 0, stream>>>(x3, out);
}

// Round 4
// 256.509 us; speedup vs baseline: 1.0214x; 1.0096x over previous
//
#include <hip/hip_runtime.h>

// WaveletParsingLayer: per-row stable stream compaction.
// x3[B,C,L] -> out[B,C,KEEP], dropping elements == FILLER (10.1f), order-preserving.
// x1, x2 are unused by the reference.
//
// R4: R2/R3 post-mortem showed the limiter is scattered scalar global stores
// (~48 address-diverged global_store_dword per thread; ~128 cyc each in the
// memory pipe). Fix: scatter survivors into a 48 KB LDS staging buffer
// (near-consecutive positions -> ~2-way bank aliasing, free), then copy out
// with perfectly coalesced float4 stores (12 per thread).
// LDS 49.4 KB -> 3 blocks/CU residency; acceptable since we're store-pipe
// bound, not occupancy bound.

#define FILLER_VAL 10.1f
constexpr int L_LEN    = 16384;
constexpr int KEEP_LEN = 12288;
constexpr int BLOCK    = 256;          // 4 waves of 64
constexpr int NW       = BLOCK / 64;   // waves per block
constexpr int CHUNK    = BLOCK * 4;    // 1024 elements per chunk
constexpr int NC       = L_LEN / CHUNK; // 16 chunks per row

__global__ __launch_bounds__(BLOCK) void compact_rows_kernel(
    const float* __restrict__ x3, float* __restrict__ out)
{
    const int row = blockIdx.x;
    const float* __restrict__ in = x3 + (size_t)row * L_LEN;
    float* __restrict__ o = out + (size_t)row * KEEP_LEN;

    const int tid  = threadIdx.x;
    const int lane = tid & 63;
    const int wid  = tid >> 6;
    const unsigned long long lt = (1ULL << lane) - 1ULL;

    __shared__ float stage[KEEP_LEN];   // 48 KB survivor staging
    __shared__ int wtot[NC][NW];        // per-chunk per-wave survivor counts

    // ---- Load entire row (16 float4/thread, independent loads).
    float4 v[NC];
    #pragma unroll
    for (int c = 0; c < NC; ++c)
        v[c] = *reinterpret_cast<const float4*>(in + c * CHUNK + tid * 4);

    // ---- Ballot counts. Element order: idx = c*1024 + wid*256 + lane*4 + j.
    int before[NC];
    #pragma unroll
    for (int c = 0; c < NC; ++c) {
        unsigned long long m0 = __ballot(v[c].x != FILLER_VAL);
        unsigned long long m1 = __ballot(v[c].y != FILLER_VAL);
        unsigned long long m2 = __ballot(v[c].z != FILLER_VAL);
        unsigned long long m3 = __ballot(v[c].w != FILLER_VAL);
        before[c] = __popcll(m0 & lt) + __popcll(m1 & lt)
                  + __popcll(m2 & lt) + __popcll(m3 & lt);
        if (lane == 0)
            wtot[c][wid] = __popcll(m0) + __popcll(m1)
                         + __popcll(m2) + __popcll(m3);
    }
    __syncthreads();   // barrier 1: wtot visible

    // ---- Prefix over (chunk, wave) + scatter survivors into LDS stage.
    int run = 0;
    #pragma unroll
    for (int c = 0; c < NC; ++c) {
        int wb = run;
        #pragma unroll
        for (int w = 0; w < NW; ++w) {
            int t = wtot[c][w];
            if (w < wid) wb += t;
            run += t;
        }
        int pos = wb + before[c];
        if (v[c].x != FILLER_VAL) { if (pos < KEEP_LEN) stage[pos] = v[c].x; ++pos; }
        if (v[c].y != FILLER_VAL) { if (pos < KEEP_LEN) stage[pos] = v[c].y; ++pos; }
        if (v[c].z != FILLER_VAL) { if (pos < KEEP_LEN) stage[pos] = v[c].z; ++pos; }
        if (v[c].w != FILLER_VAL) { if (pos < KEEP_LEN) stage[pos] = v[c].w; ++pos; }
    }
    __syncthreads();   // barrier 2: stage complete

    // ---- Coalesced copy-out: 12288 floats = 12 float4 per thread.
    #pragma unroll
    for (int k = 0; k < KEEP_LEN / (BLOCK * 4); ++k) {
        const int idx = (k * BLOCK + tid) * 4;
        float4 val = *reinterpret_cast<const float4*>(&stage[idx]);
        *reinterpret_cast<float4*>(&o[idx]) = val;
    }
}

extern "C" void kernel_launch(void* const* d_in, const int* in_sizes, int n_in,
                              void* d_out, int out_size, void* d_ws, size_t ws_size,
                              hipStream_t stream)
{
    // in order: x1 [B,C,4096] f32 (unused), x2 [B,C,4096] f32 (unused),
    //           x3 [B,C,L] f32, keep_len (scalar int, value 12288)
    const float* x3 = (const float*)d_in[2];
    float* out = (float*)d_out;

    const int rows = in_sizes[2] / L_LEN;  // B*C = 2048

    compact_rows_kernel<<<rows, BLOCK, 0, stream>>>(x3, out);
}